// Round 1
// 1570.069 us; speedup vs baseline: 1.0571x; 1.0571x over previous
//
#include <hip/hip_runtime.h>
#include <math.h>

// Problem constants
#define NROWS 20000
#define KDIM  9480     // T*D
#define GEDIM 128      // G*E
#define GNUM  8
#define ENUM  16

// Router GEMM tiling (MFMA path)
#define BM 128
#define BK 32
#define NTHREADS 256
#define WPAD 9504               // KDIM rounded up to multiple of BK; pad is zero-filled
#define WRELEM (GEDIM * WPAD)   // elements of one transposed bf16 Wr array
#define TROWS 4                 // rows per tail block (one wave each)

using bf16x8 = __attribute__((ext_vector_type(8))) short;
using f32x4  = __attribute__((ext_vector_type(4))) float;

#define MFMA16(a, b, c) __builtin_amdgcn_mfma_f32_16x16x32_bf16((a), (b), (c), 0, 0, 0)

// RNE fp32 -> bf16, returning the exact residual (f - bf16(f)).
__device__ __forceinline__ unsigned short bsplit(float f, float& rem) {
    unsigned u = __float_as_uint(f);
    unsigned r = u + 0x7fffu + ((u >> 16) & 1u);
    unsigned short h = (unsigned short)(r >> 16);
    rem = f - __uint_as_float((unsigned)h << 16);
    return h;
}

__device__ __forceinline__ void split3(float f, unsigned short& h,
                                       unsigned short& m, unsigned short& l) {
    float r1, r2, r3;
    h = bsplit(f, r1);
    m = bsplit(r1, r2);
    l = bsplit(r2, r3);
}

// ---------------------------------------------------------------------------
// Kernel 0: Wr fp32 [KDIM][128] -> transposed triple-split bf16 [128][WPAD].
// Pad region (k in [KDIM, WPAD)) is written as zeros so the router can read
// it unguarded (garbage bf16 could be NaN; NaN * 0 would poison the acc).
// ---------------------------------------------------------------------------
__global__ void wr_convert(const float* __restrict__ Wr,
                           unsigned short* __restrict__ Wh,
                           unsigned short* __restrict__ Wm,
                           unsigned short* __restrict__ Wl)
{
    __shared__ float tile[128][GEDIM + 4];   // +4 breaks pow2 stride on transpose read
    const int tid = threadIdx.x;
    const int k0  = blockIdx.x * 128;
#pragma unroll
    for (int i = 0; i < 16; ++i) {
        int fid = tid + i * 256;             // 4096 float4 = 128k x 128c
        int kk  = fid >> 5;
        int c4  = (fid & 31) * 4;
        float4 v = make_float4(0.f, 0.f, 0.f, 0.f);
        if (k0 + kk < KDIM)
            v = *(const float4*)(Wr + (size_t)(k0 + kk) * GEDIM + c4);
        *(float4*)&tile[kk][c4] = v;
    }
    __syncthreads();
    const int c = tid >> 1, half = tid & 1;
#pragma unroll
    for (int j4 = 0; j4 < 16; ++j4) {
        int kb = half * 64 + j4 * 4;
        if (k0 + kb >= WPAD) continue;
        ushort4 hv, mv, lv;
#pragma unroll
        for (int jj = 0; jj < 4; ++jj) {
            float f = tile[kb + jj][c];
            split3(f, ((unsigned short*)&hv)[jj], ((unsigned short*)&mv)[jj],
                      ((unsigned short*)&lv)[jj]);
        }
        size_t off = (size_t)c * WPAD + (k0 + kb);
        *(ushort4*)(Wh + off) = hv;
        *(ushort4*)(Wm + off) = mv;
        *(ushort4*)(Wl + off) = lv;
    }
}

// ---------------------------------------------------------------------------
// Kernel 1: split-K router GEMM on the matrix pipe.
// fp32 emulated as triple-split bf16: x = xh+xm+xl, w = wh+wm+wl (each level
// RNE-rounded, residual exact). Keep the 6 cross terms >= 2^-24 scale:
//   hh, hm, mh, hl, lh, mm  -> representation error ~2^-24, fp32 MFMA accum.
// MFMA f32_16x16x32_bf16 layouts (verified, see guide §3):
//   A: row=lane&15, k=(lane>>4)*8+j    B: col=lane&15, k=(lane>>4)*8+j
//   D: col=lane&15, row=(lane>>4)*4+reg
// Block 128x128, 4 waves (2x2), wave tile 64x64 = 4x4 16x16 frags.
// ---------------------------------------------------------------------------
__global__ __launch_bounds__(NTHREADS, 2) void router_gemm(
    const float* __restrict__ x,
    const unsigned short* __restrict__ Wh,
    const unsigned short* __restrict__ Wm,
    const unsigned short* __restrict__ Wl,
    float* __restrict__ partial, int ipc)
{
    __shared__ __align__(16) unsigned short sXh[BM][BK], sXm[BM][BK], sXl[BM][BK];
    __shared__ __align__(16) unsigned short sWh[GEDIM][BK], sWm[GEDIM][BK], sWl[GEDIM][BK];

    const int tid  = threadIdx.x;
    const int lane = tid & 63;
    const int wid  = tid >> 6;
    const int wm_  = wid >> 1, wn_ = wid & 1;
    const int fr   = lane & 15, fq = lane >> 4;
    const int m0   = blockIdx.x * BM;

    const int kstart = blockIdx.y * ipc * BK;
    const int kend   = min(kstart + ipc * BK, WPAD);

    f32x4 acc[4][4];
#pragma unroll
    for (int i = 0; i < 4; ++i)
#pragma unroll
        for (int j = 0; j < 4; ++j) acc[i][j] = f32x4{0.f, 0.f, 0.f, 0.f};

    float4 xr[4];        // staged x tile (fp32, converted at write time)
    uint4  wr[3][2];     // staged pre-converted Wr tile (bf16 x8 chunks)

    auto load_tile = [&](int k0) {
#pragma unroll
        for (int i = 0; i < 4; ++i) {
            int fid = tid + i * NTHREADS;        // 1024 float4 = 128r x 32k
            int r = fid >> 3, kc = (fid & 7) * 4;
            int grow = m0 + r, gk = k0 + kc;
            float4 v = make_float4(0.f, 0.f, 0.f, 0.f);
            if (grow < NROWS && gk < KDIM)
                v = *(const float4*)(x + (size_t)grow * KDIM + gk);
            xr[i] = v;
        }
#pragma unroll
        for (int i = 0; i < 2; ++i) {
            int fid = tid + i * NTHREADS;        // 512 chunks = 128c x 4(k8)
            int cc = fid >> 2, kq = (fid & 3) * 8;
            size_t off = (size_t)cc * WPAD + k0 + kq;   // pad makes this unguarded-safe
            wr[0][i] = *(const uint4*)(Wh + off);
            wr[1][i] = *(const uint4*)(Wm + off);
            wr[2][i] = *(const uint4*)(Wl + off);
        }
    };

    load_tile(kstart);

    for (int k0 = kstart; k0 < kend; k0 += BK) {
        // ---- stage regs -> LDS (convert x to 3 bf16 levels)
#pragma unroll
        for (int i = 0; i < 4; ++i) {
            int fid = tid + i * NTHREADS;
            int r = fid >> 3, kc = (fid & 7) * 4;
            float4 v = xr[i];
            ushort4 hv, mv, lv;
            split3(v.x, hv.x, mv.x, lv.x);
            split3(v.y, hv.y, mv.y, lv.y);
            split3(v.z, hv.z, mv.z, lv.z);
            split3(v.w, hv.w, mv.w, lv.w);
            *(ushort4*)&sXh[r][kc] = hv;
            *(ushort4*)&sXm[r][kc] = mv;
            *(ushort4*)&sXl[r][kc] = lv;
        }
#pragma unroll
        for (int i = 0; i < 2; ++i) {
            int fid = tid + i * NTHREADS;
            int cc = fid >> 2, kq = (fid & 3) * 8;
            *(uint4*)&sWh[cc][kq] = wr[0][i];
            *(uint4*)&sWm[cc][kq] = wr[1][i];
            *(uint4*)&sWl[cc][kq] = wr[2][i];
        }
        __syncthreads();

        // issue next tile's global loads now; latency hides under the MFMAs
        if (k0 + BK < kend) load_tile(k0 + BK);

        // ---- MFMA compute (one k32 step, 96 MFMAs/wave)
        bf16x8 ah[4], am[4], al[4];
#pragma unroll
        for (int mt = 0; mt < 4; ++mt) {
            int r = wm_ * 64 + mt * 16 + fr;
            ah[mt] = *(const bf16x8*)&sXh[r][fq * 8];
            am[mt] = *(const bf16x8*)&sXm[r][fq * 8];
            al[mt] = *(const bf16x8*)&sXl[r][fq * 8];
        }
#pragma unroll
        for (int nt = 0; nt < 4; ++nt) {
            int cidx = wn_ * 64 + nt * 16 + fr;
            bf16x8 bh = *(const bf16x8*)&sWh[cidx][fq * 8];
            bf16x8 bm = *(const bf16x8*)&sWm[cidx][fq * 8];
            bf16x8 bl = *(const bf16x8*)&sWl[cidx][fq * 8];
#pragma unroll
            for (int mt = 0; mt < 4; ++mt) {
                f32x4 a = acc[mt][nt];
                a = MFMA16(ah[mt], bh, a);   // 2^0
                a = MFMA16(ah[mt], bm, a);   // 2^-8
                a = MFMA16(am[mt], bh, a);   // 2^-8
                a = MFMA16(ah[mt], bl, a);   // 2^-16
                a = MFMA16(al[mt], bh, a);   // 2^-16
                a = MFMA16(am[mt], bm, a);   // 2^-16
                acc[mt][nt] = a;
            }
        }
        __syncthreads();
    }

    // ---- store partials (always store: ws is poisoned)
    float* pbase = partial + (size_t)blockIdx.y * NROWS * GEDIM;
#pragma unroll
    for (int mt = 0; mt < 4; ++mt) {
#pragma unroll
        for (int j = 0; j < 4; ++j) {
            int row = m0 + wm_ * 64 + mt * 16 + fq * 4 + j;
            if (row < NROWS) {
#pragma unroll
                for (int nt = 0; nt < 4; ++nt) {
                    int col = wn_ * 64 + nt * 16 + fr;
                    pbase[(size_t)row * GEDIM + col] = acc[mt][nt][j];
                }
            }
        }
    }
}

// ---------------------------------------------------------------------------
// Kernel 2: per-row tail.  TROWS rows per 256-thread block, one wave per row
// (better residency than 64-thread blocks).  Reduce split-K partials -> h;
// top-2 (jax tie-break); only the <=2 selected groups' expert+attn path; gate.
// ---------------------------------------------------------------------------
__global__ __launch_bounds__(256, 4) void tail_kernel(
    const float* __restrict__ partial, int S,
    const float* __restrict__ br,
    const float* __restrict__ We, const float* __restrict__ be,
    const float* __restrict__ Wq, const float* __restrict__ bq,
    const float* __restrict__ Wk, const float* __restrict__ bk,
    const float* __restrict__ Wv, const float* __restrict__ bv,
    const float* __restrict__ Wo, const float* __restrict__ bo,
    float* __restrict__ out)
{
    const int w    = threadIdx.x >> 6;
    const int lane = threadIdx.x & 63;
    const int n    = blockIdx.x * TROWS + w;   // 20000 = 5000*4 exact

    __shared__ __align__(16) float hbuf[TROWS][GEDIM];
    __shared__ __align__(16) float eobuf[TROWS][2][ENUM];
    __shared__ float qbuf[TROWS][2][ENUM], kbuf[TROWS][2][ENUM], vbuf[TROWS][2][ENUM];
    __shared__ float abuf[TROWS][2][ENUM];
    __shared__ __align__(16) float attbuf[TROWS][2][ENUM];
    __shared__ float obuf[TROWS][2];

    // 1. reduce split-K partials + bias
    float h0 = br[lane];
    float h1 = br[lane + 64];
    for (int s = 0; s < S; ++s) {
        const float* p = partial + ((size_t)s * NROWS + n) * GEDIM;
        h0 += p[lane];
        h1 += p[lane + 64];
    }
    hbuf[w][lane]      = h0;
    hbuf[w][lane + 64] = h1;

    // 2. top-2 over 128 values (value desc, index asc on ties = jax.lax.top_k)
    float v1, v2; int i1, i2;
    if (h1 > h0) { v1 = h1; i1 = lane + 64; v2 = h0; i2 = lane; }
    else         { v1 = h0; i1 = lane;      v2 = h1; i2 = lane + 64; }
#pragma unroll
    for (int m = 1; m <= 32; m <<= 1) {
        float ov1 = __shfl_xor(v1, m);
        float ov2 = __shfl_xor(v2, m);
        int   oi1 = __shfl_xor(i1, m);
        int   oi2 = __shfl_xor(i2, m);
        bool a_first = (v1 > ov1) || (v1 == ov1 && i1 < oi1);
        float w1v = a_first ? v1  : ov1;  int w1i = a_first ? i1  : oi1;
        float l1v = a_first ? ov1 : v1;   int l1i = a_first ? oi1 : i1;
        float w2v = a_first ? v2  : ov2;  int w2i = a_first ? i2  : oi2;
        bool s_first = (w2v > l1v) || (w2v == l1v && w2i < l1i);
        v1 = w1v; i1 = w1i;
        v2 = s_first ? w2v : l1v;
        i2 = s_first ? w2i : l1i;
    }
    float t  = expf(v2 - v1);
    float wa = 1.0f / (1.0f + t);
    float wb = 1.0f - wa;

    const int ga = i1 >> 4, fa = i1 & 15;
    const int gb = i2 >> 4, fb = i2 & 15;

    __syncthreads();   // hbuf visible

    // 3. expert outputs for the two selected groups (float4-vectorized dots)
    {
        int e   = (lane >> 1) & 15;
        int sel = lane >> 5;
        int q   = lane & 1;              // which half of the 128-dot
        int g   = sel ? gb : ga;
        const float4* w4 = (const float4*)(We + (size_t)(g * ENUM + e) * GEDIM + q * 64);
        const float4* h4 = (const float4*)&hbuf[w][q * 64];
        float acc = 0.f;
#pragma unroll
        for (int j = 0; j < 16; ++j) {
            float4 a = w4[j], b = h4[j];
            acc += a.x * b.x + a.y * b.y + a.z * b.z + a.w * b.w;
        }
        acc += __shfl_xor(acc, 1);
        if (q == 0) eobuf[w][sel][e] = acc + be[g * ENUM + e];
    }
    __syncthreads();

    // 4. Q,K,V projections (torch [out,in] layout)
    if (lane < 32) {
        int f   = lane & 15;
        int sel = lane >> 4;
        int g   = sel ? gb : ga;
        int base = (g * ENUM + f) * ENUM;
        const float4* q4 = (const float4*)(Wq + base);
        const float4* k4 = (const float4*)(Wk + base);
        const float4* v4 = (const float4*)(Wv + base);
        float q = bq[g * ENUM + f];
        float k = bk[g * ENUM + f];
        float v = bv[g * ENUM + f];
#pragma unroll
        for (int j = 0; j < 4; ++j) {
            float4 e4 = *(const float4*)&eobuf[w][sel][j * 4];
            float4 aa = q4[j]; q += e4.x*aa.x + e4.y*aa.y + e4.z*aa.z + e4.w*aa.w;
            float4 bb = k4[j]; k += e4.x*bb.x + e4.y*bb.y + e4.z*bb.z + e4.w*bb.w;
            float4 cc = v4[j]; v += e4.x*cc.x + e4.y*cc.y + e4.z*cc.z + e4.w*cc.w;
        }
        qbuf[w][sel][f] = q;
        kbuf[w][sel][f] = k;
        vbuf[w][sel][f] = v;
    }
    __syncthreads();

    // 5. scores (head_dim is the seq axis) + softmax over e
    if (lane < 32) {
        int sel = lane >> 4;
        int d   = (lane >> 2) & 3;
        int e   = lane & 3;
        float sc = 0.f;
#pragma unroll
        for (int hh = 0; hh < 4; ++hh)
            sc += qbuf[w][sel][hh * 4 + d] * kbuf[w][sel][hh * 4 + e];
        sc *= 0.5f;   // 1/sqrt(DH)
        float mx = fmaxf(sc, __shfl_xor(sc, 1));
        mx = fmaxf(mx, __shfl_xor(mx, 2));
        float p = expf(sc - mx);
        float sum = p + __shfl_xor(p, 1);
        sum += __shfl_xor(sum, 2);
        abuf[w][sel][d * 4 + e] = p / sum;
    }
    __syncthreads();

    // 6. att, written back transposed to flat E
    if (lane < 32) {
        int sel = lane >> 4;
        int d   = (lane >> 2) & 3;
        int hh  = lane & 3;
        float a = 0.f;
#pragma unroll
        for (int e2 = 0; e2 < 4; ++e2)
            a += abuf[w][sel][d * 4 + e2] * vbuf[w][sel][hh * 4 + e2];
        attbuf[w][sel][hh * 4 + d] = a;
    }
    __syncthreads();

    // 7. only the two needed output-proj elements, then gate
    if (lane < 2) {
        int sel = lane;
        int g = sel ? gb : ga;
        int f = sel ? fb : fa;
        int base = (g * ENUM + f) * ENUM;
        const float4* o4 = (const float4*)(Wo + base);
        float o = bo[g * ENUM + f];
#pragma unroll
        for (int j = 0; j < 4; ++j) {
            float4 aa = o4[j];
            float4 tt = *(const float4*)&attbuf[w][sel][j * 4];
            o += tt.x*aa.x + tt.y*aa.y + tt.z*aa.z + tt.w*aa.w;
        }
        obuf[w][sel] = o;
    }
    __syncthreads();
    if (lane == 0)
        out[n] = wa * obuf[w][0] + wb * obuf[w][1];
}

extern "C" void kernel_launch(void* const* d_in, const int* in_sizes, int n_in,
                              void* d_out, int out_size, void* d_ws, size_t ws_size,
                              hipStream_t stream)
{
    const float* x  = (const float*)d_in[0];
    const float* Wr = (const float*)d_in[1];
    const float* br = (const float*)d_in[2];
    const float* We = (const float*)d_in[3];
    const float* be = (const float*)d_in[4];
    const float* Wq = (const float*)d_in[5];
    const float* bq = (const float*)d_in[6];
    const float* Wk = (const float*)d_in[7];
    const float* bk = (const float*)d_in[8];
    const float* Wv = (const float*)d_in[9];
    const float* bv = (const float*)d_in[10];
    const float* Wo = (const float*)d_in[11];
    const float* bo = (const float*)d_in[12];
    float* out = (float*)d_out;

    // ws layout: [Wh][Wm][Wl][partial x S]
    unsigned short* Wh = (unsigned short*)d_ws;
    unsigned short* Wm = Wh + WRELEM;
    unsigned short* Wl = Wm + WRELEM;
    const size_t wr_bytes = (size_t)3 * WRELEM * sizeof(unsigned short); // 7.30 MB
    float* partial = (float*)((char*)d_ws + wr_bytes);

    const size_t slice = (size_t)NROWS * GEDIM * sizeof(float);          // 10.24 MB
    int S = (int)((ws_size - wr_bytes) / slice);
    if (S > 4) S = 4;
    if (S < 1) S = 1;

    const int total_iters = WPAD / BK;            // 297
    const int ipc = (total_iters + S - 1) / S;

    wr_convert<<<dim3((WPAD + 127) / 128), 256, 0, stream>>>(Wr, Wh, Wm, Wl);

    dim3 ggrid((NROWS + BM - 1) / BM, S);         // 157 x S
    router_gemm<<<ggrid, NTHREADS, 0, stream>>>(x, Wh, Wm, Wl, partial, ipc);

    tail_kernel<<<NROWS / TROWS, 256, 0, stream>>>(partial, S, br,
        We, be, Wq, bq, Wk, bk, Wv, bv, Wo, bo, out);
}